// Round 1
// baseline (1181.483 us; speedup 1.0000x reference)
//
#include <hip/hip_runtime.h>
#include <cstdint>

// GraphSAGE 2-layer, N=200000 nodes, E=6400000 edges, F 16->40->24, fp32.
// Strategy: build CSR (tgt-sorted) adjacency once per call, then both layers
// are gather-based (no float atomics), fused aggregation+GEMM+activation.

#define N_NODESC 200000
#define N_EDGESC 6400000
#define F_INC 16
#define F_HC 40
#define F_OUTC 24

constexpr int SCAN_BLOCK = 1024;
constexpr int NBLK = (N_NODESC + SCAN_BLOCK - 1) / SCAN_BLOCK; // 196

// ---------------- CSR build ----------------

__global__ void deg_kernel(const int* __restrict__ tgt, int* __restrict__ deg) {
    int i = blockIdx.x * blockDim.x + threadIdx.x;
    int stride = gridDim.x * blockDim.x;
    for (; i < N_EDGESC; i += stride) {
        atomicAdd(&deg[tgt[i]], 1);
    }
}

__global__ void scan1_kernel(const int* __restrict__ deg, float* __restrict__ inv_deg,
                             int* __restrict__ row_ptr, int* __restrict__ bsum) {
    __shared__ int tmp[SCAN_BLOCK];
    int t = threadIdx.x;
    int idx = blockIdx.x * SCAN_BLOCK + t;
    int d = (idx < N_NODESC) ? deg[idx] : 0;
    if (idx < N_NODESC) inv_deg[idx] = (d > 0) ? 1.0f / (float)d : 0.0f;
    tmp[t] = d;
    __syncthreads();
    // Hillis-Steele inclusive scan
    for (int off = 1; off < SCAN_BLOCK; off <<= 1) {
        int v = (t >= off) ? tmp[t - off] : 0;
        __syncthreads();
        tmp[t] += v;
        __syncthreads();
    }
    if (idx < N_NODESC) row_ptr[idx] = tmp[t] - d; // exclusive
    if (t == SCAN_BLOCK - 1) bsum[blockIdx.x] = tmp[t];
}

__global__ void scan2_kernel(int* __restrict__ bsum) {
    if (blockIdx.x == 0 && threadIdx.x == 0) {
        int acc = 0;
        for (int i = 0; i < NBLK; i++) { int v = bsum[i]; bsum[i] = acc; acc += v; }
    }
}

__global__ void scan3_kernel(int* __restrict__ row_ptr, const int* __restrict__ bsum) {
    int idx = blockIdx.x * SCAN_BLOCK + threadIdx.x;
    if (idx < N_NODESC) row_ptr[idx] += bsum[blockIdx.x];
    if (idx == 0) row_ptr[N_NODESC] = N_EDGESC;
}

__global__ void fill_kernel(const int* __restrict__ src, const int* __restrict__ tgt,
                            const int* __restrict__ row_ptr, int* __restrict__ fill_pos,
                            int* __restrict__ csr_src) {
    int i = blockIdx.x * blockDim.x + threadIdx.x;
    int stride = gridDim.x * blockDim.x;
    for (; i < N_EDGESC; i += stride) {
        int t = tgt[i];
        int p = row_ptr[t] + atomicAdd(&fill_pos[t], 1);
        csr_src[p] = src[i];
    }
}

// ---------------- Layer 1: agg(x)@W1l + b1 + x@W1r, ReLU -> h ----------------

__global__ __launch_bounds__(256) void layer1_kernel(
    const float* __restrict__ x, const int* __restrict__ row_ptr,
    const int* __restrict__ csr_src, const float* __restrict__ inv_deg,
    const float* __restrict__ W1l, const float* __restrict__ b1,
    const float* __restrict__ W1r, float* __restrict__ h) {
    __shared__ float sWl[F_INC][F_HC];
    __shared__ float sWr[F_INC][F_HC];
    __shared__ float sb[F_HC];
    for (int i = threadIdx.x; i < F_INC * F_HC; i += blockDim.x) {
        sWl[i / F_HC][i % F_HC] = W1l[i];
        sWr[i / F_HC][i % F_HC] = W1r[i];
    }
    if (threadIdx.x < F_HC) sb[threadIdx.x] = b1[threadIdx.x];
    __syncthreads();

    int n = blockIdx.x * blockDim.x + threadIdx.x;
    if (n >= N_NODESC) return;

    float agg[F_INC];
#pragma unroll
    for (int k = 0; k < F_INC; k++) agg[k] = 0.0f;

    int e0 = row_ptr[n], e1 = row_ptr[n + 1];
    for (int e = e0; e < e1; e++) {
        int s = csr_src[e];
        const float4* xs = (const float4*)(x + (size_t)s * F_INC);
#pragma unroll
        for (int q = 0; q < F_INC / 4; q++) {
            float4 v = xs[q];
            agg[q * 4 + 0] += v.x; agg[q * 4 + 1] += v.y;
            agg[q * 4 + 2] += v.z; agg[q * 4 + 3] += v.w;
        }
    }

    float idg = inv_deg[n];
#pragma unroll
    for (int k = 0; k < F_INC; k++) agg[k] *= idg;

    float xr[F_INC];
    const float4* xn = (const float4*)(x + (size_t)n * F_INC);
#pragma unroll
    for (int q = 0; q < F_INC / 4; q++) {
        float4 v = xn[q];
        xr[q * 4 + 0] = v.x; xr[q * 4 + 1] = v.y;
        xr[q * 4 + 2] = v.z; xr[q * 4 + 3] = v.w;
    }

    float out[F_HC];
#pragma unroll
    for (int f = 0; f < F_HC; f++) out[f] = sb[f];
#pragma unroll
    for (int k = 0; k < F_INC; k++) {
        float a = agg[k], b = xr[k];
#pragma unroll
        for (int f = 0; f < F_HC; f++) out[f] += a * sWl[k][f] + b * sWr[k][f];
    }

    float4* hn = (float4*)(h + (size_t)n * F_HC); // 160B rows, 16B aligned
#pragma unroll
    for (int q = 0; q < F_HC / 4; q++) {
        float4 v;
        v.x = fmaxf(out[q * 4 + 0], 0.0f);
        v.y = fmaxf(out[q * 4 + 1], 0.0f);
        v.z = fmaxf(out[q * 4 + 2], 0.0f);
        v.w = fmaxf(out[q * 4 + 3], 0.0f);
        hn[q] = v;
    }
}

// -------- Layer 2: agg(h)@W2l + b2 + h@W2r, log_softmax -> out --------

__global__ __launch_bounds__(256) void layer2_kernel(
    const float* __restrict__ h, const int* __restrict__ row_ptr,
    const int* __restrict__ csr_src, const float* __restrict__ inv_deg,
    const float* __restrict__ W2l, const float* __restrict__ b2,
    const float* __restrict__ W2r, float* __restrict__ out) {
    __shared__ float sWl[F_HC][F_OUTC];
    __shared__ float sWr[F_HC][F_OUTC];
    __shared__ float sb[F_OUTC];
    for (int i = threadIdx.x; i < F_HC * F_OUTC; i += blockDim.x) {
        sWl[i / F_OUTC][i % F_OUTC] = W2l[i];
        sWr[i / F_OUTC][i % F_OUTC] = W2r[i];
    }
    if (threadIdx.x < F_OUTC) sb[threadIdx.x] = b2[threadIdx.x];
    __syncthreads();

    int n = blockIdx.x * blockDim.x + threadIdx.x;
    if (n >= N_NODESC) return;

    float agg[F_HC];
#pragma unroll
    for (int k = 0; k < F_HC; k++) agg[k] = 0.0f;

    int e0 = row_ptr[n], e1 = row_ptr[n + 1];
    for (int e = e0; e < e1; e++) {
        int s = csr_src[e];
        const float4* hs = (const float4*)(h + (size_t)s * F_HC);
#pragma unroll
        for (int q = 0; q < F_HC / 4; q++) {
            float4 v = hs[q];
            agg[q * 4 + 0] += v.x; agg[q * 4 + 1] += v.y;
            agg[q * 4 + 2] += v.z; agg[q * 4 + 3] += v.w;
        }
    }

    float idg = inv_deg[n];
#pragma unroll
    for (int k = 0; k < F_HC; k++) agg[k] *= idg;

    float hr[F_HC];
    const float4* hn = (const float4*)(h + (size_t)n * F_HC);
#pragma unroll
    for (int q = 0; q < F_HC / 4; q++) {
        float4 v = hn[q];
        hr[q * 4 + 0] = v.x; hr[q * 4 + 1] = v.y;
        hr[q * 4 + 2] = v.z; hr[q * 4 + 3] = v.w;
    }

    float o[F_OUTC];
#pragma unroll
    for (int f = 0; f < F_OUTC; f++) o[f] = sb[f];
#pragma unroll
    for (int k = 0; k < F_HC; k++) {
        float a = agg[k], b = hr[k];
#pragma unroll
        for (int f = 0; f < F_OUTC; f++) o[f] += a * sWl[k][f] + b * sWr[k][f];
    }

    // log_softmax over 24 classes
    float m = o[0];
#pragma unroll
    for (int f = 1; f < F_OUTC; f++) m = fmaxf(m, o[f]);
    float ssum = 0.0f;
#pragma unroll
    for (int f = 0; f < F_OUTC; f++) ssum += __expf(o[f] - m);
    float lse = m + __logf(ssum);

    float4* on = (float4*)(out + (size_t)n * F_OUTC); // 96B rows, 16B aligned
#pragma unroll
    for (int q = 0; q < F_OUTC / 4; q++) {
        float4 v;
        v.x = o[q * 4 + 0] - lse;
        v.y = o[q * 4 + 1] - lse;
        v.z = o[q * 4 + 2] - lse;
        v.w = o[q * 4 + 3] - lse;
        on[q] = v;
    }
}

// ---------------- launch ----------------

extern "C" void kernel_launch(void* const* d_in, const int* in_sizes, int n_in,
                              void* d_out, int out_size, void* d_ws, size_t ws_size,
                              hipStream_t stream) {
    const float* x   = (const float*)d_in[0];
    const int* eidx  = (const int*)d_in[1]; // int32 per harness convention
    const float* W1l = (const float*)d_in[2];
    const float* b1  = (const float*)d_in[3];
    const float* W1r = (const float*)d_in[4];
    const float* W2l = (const float*)d_in[5];
    const float* b2  = (const float*)d_in[6];
    const float* W2r = (const float*)d_in[7];
    float* out = (float*)d_out;

    const int* src = eidx;
    const int* tgt = eidx + N_EDGESC;

    // workspace layout (256B aligned)
    char* ws = (char*)d_ws;
    size_t off = 0;
    auto alloc = [&](size_t bytes) {
        size_t o = off;
        off = (off + bytes + 255) & ~(size_t)255;
        return o;
    };
    int*   deg      = (int*)(ws + alloc((size_t)N_NODESC * 4));
    int*   fill_pos = (int*)(ws + alloc((size_t)N_NODESC * 4)); // adjacent to deg
    float* inv_deg  = (float*)(ws + alloc((size_t)N_NODESC * 4));
    int*   row_ptr  = (int*)(ws + alloc((size_t)(N_NODESC + 1) * 4));
    int*   bsum     = (int*)(ws + alloc((size_t)NBLK * 4));
    int*   csr_src  = (int*)(ws + alloc((size_t)N_EDGESC * 4));
    float* h        = (float*)(ws + alloc((size_t)N_NODESC * F_HC * 4));
    (void)ws_size;

    // zero deg + fill_pos (contiguous, each padded to 256B multiple)
    hipMemsetAsync(deg, 0, ((size_t)N_NODESC * 4 + 255 & ~(size_t)255) * 2, stream);

    const int TB = 256;
    const int edgeBlocks = 2560;
    deg_kernel<<<edgeBlocks, TB, 0, stream>>>(tgt, deg);
    scan1_kernel<<<NBLK, SCAN_BLOCK, 0, stream>>>(deg, inv_deg, row_ptr, bsum);
    scan2_kernel<<<1, 64, 0, stream>>>(bsum);
    scan3_kernel<<<NBLK, SCAN_BLOCK, 0, stream>>>(row_ptr, bsum);
    fill_kernel<<<edgeBlocks, TB, 0, stream>>>(src, tgt, row_ptr, fill_pos, csr_src);

    const int nodeBlocks = (N_NODESC + TB - 1) / TB;
    layer1_kernel<<<nodeBlocks, TB, 0, stream>>>(x, row_ptr, csr_src, inv_deg,
                                                 W1l, b1, W1r, h);
    layer2_kernel<<<nodeBlocks, TB, 0, stream>>>(h, row_ptr, csr_src, inv_deg,
                                                 W2l, b2, W2r, out);
}

// Round 8
// 879.004 us; speedup vs baseline: 1.3441x; 1.3441x over previous
//
#include <hip/hip_runtime.h>
#include <hip/hip_fp16.h>
#include <cstdint>

// GraphSAGE 2-layer, N=200000, E=6400000, F 16->40->24, fp32 in/out.
// CSR gather with algebraic push-through of W2l/W2r:
//   g = h@W2l (fp16, 64B-stride rows -> 1 line per random gather)
//   r = h@W2r + b2 (fp32, streamed)
//   layer2: out = log_softmax(mean(g[src]) + r[n]) -- h never materialized.
// Gather kernels use 4 lanes/node + unroll-2 for latency hiding / balance.
// deg + fill are XCD-bucketed: 8 node-buckets (deg slice 100KB, csr slice
// 3.2MB < 4MB L2/XCD); blocks with blockIdx.x%8==b commit only bucket-b
// targets -> scattered atomics/stores stay XCD-L2-resident. Edge list is
// re-read 8x but absorbed by the 256MB L3.

#define N_NODESC 200000
#define N_EDGESC 6400000
#define F_INC 16
#define F_HC 40
#define F_OUTC 24

constexpr int SCAN_BLOCK = 1024;
constexpr int NBLK = (N_NODESC + SCAN_BLOCK - 1) / SCAN_BLOCK; // 196
constexpr int NBUCKET = 8;
constexpr int BUCKET_SZ = N_NODESC / NBUCKET; // 25000

// ---------------- CSR build ----------------

// XCD-bucketed degree count: gridDim.x must be a multiple of 8. Bucket
// b = blockIdx.x & 7 (aligned with HW round-robin XCD dispatch; locality
// only, correctness independent of mapping). Bucket-b blocks grid-stride
// the FULL edge list, counting only targets in [b*BUCKET_SZ,(b+1)*BUCKET_SZ).
__global__ void deg_kernel(const int* __restrict__ tgt, int* __restrict__ deg) {
    constexpr int NV = N_EDGESC / 4; // 1.6M int4s
    const int4* t4 = (const int4*)tgt;
    int bucket = blockIdx.x & (NBUCKET - 1);
    int slot = blockIdx.x >> 3;
    int nslots = gridDim.x >> 3;
    int lo = bucket * BUCKET_SZ;
    int hi = lo + BUCKET_SZ;
    int i = slot * blockDim.x + threadIdx.x;
    int stride = nslots * blockDim.x;
    for (; i < NV; i += stride) {
        int4 t = t4[i];
        if (t.x >= lo && t.x < hi) atomicAdd(&deg[t.x], 1);
        if (t.y >= lo && t.y < hi) atomicAdd(&deg[t.y], 1);
        if (t.z >= lo && t.z < hi) atomicAdd(&deg[t.z], 1);
        if (t.w >= lo && t.w < hi) atomicAdd(&deg[t.w], 1);
    }
}

__global__ void scan1_kernel(const int* __restrict__ deg, float* __restrict__ inv_deg,
                             int* __restrict__ row_ptr, int* __restrict__ bsum) {
    __shared__ int tmp[SCAN_BLOCK];
    int t = threadIdx.x;
    int idx = blockIdx.x * SCAN_BLOCK + t;
    int d = (idx < N_NODESC) ? deg[idx] : 0;
    if (idx < N_NODESC) inv_deg[idx] = (d > 0) ? 1.0f / (float)d : 0.0f;
    tmp[t] = d;
    __syncthreads();
    for (int off = 1; off < SCAN_BLOCK; off <<= 1) {
        int v = (t >= off) ? tmp[t - off] : 0;
        __syncthreads();
        tmp[t] += v;
        __syncthreads();
    }
    if (idx < N_NODESC) row_ptr[idx] = tmp[t] - d; // exclusive within block
    if (t == SCAN_BLOCK - 1) bsum[blockIdx.x] = tmp[t];
}

// parallel block-level scan of bsum (NBLK=196 <= 256)
__global__ void scan2_kernel(int* __restrict__ bsum) {
    __shared__ int tmp[256];
    int t = threadIdx.x;
    int v = (t < NBLK) ? bsum[t] : 0;
    tmp[t] = v;
    __syncthreads();
    for (int off = 1; off < 256; off <<= 1) {
        int u = (t >= off) ? tmp[t - off] : 0;
        __syncthreads();
        tmp[t] += u;
        __syncthreads();
    }
    if (t < NBLK) bsum[t] = tmp[t] - v; // exclusive
}

__global__ void scan3_kernel(int* __restrict__ row_ptr, const int* __restrict__ bsum,
                             int* __restrict__ fill_pos) {
    int idx = blockIdx.x * SCAN_BLOCK + threadIdx.x;
    if (idx < N_NODESC) {
        int v = row_ptr[idx] + bsum[blockIdx.x];
        row_ptr[idx] = v;
        fill_pos[idx] = v;
    }
    if (idx == 0) row_ptr[N_NODESC] = N_EDGESC;
}

// XCD-bucketed fill (same decomposition as deg_kernel). Every edge is
// committed exactly once: by the one bucket containing its target.
__global__ void fill_kernel(const int* __restrict__ src, const int* __restrict__ tgt,
                            int* __restrict__ fill_pos, int* __restrict__ csr_src) {
    constexpr int NV = N_EDGESC / 4;
    const int4* t4 = (const int4*)tgt;
    const int4* s4 = (const int4*)src;
    int bucket = blockIdx.x & (NBUCKET - 1);
    int slot = blockIdx.x >> 3;
    int nslots = gridDim.x >> 3;
    int lo = bucket * BUCKET_SZ;
    int hi = lo + BUCKET_SZ;
    int i = slot * blockDim.x + threadIdx.x;
    int stride = nslots * blockDim.x;
    for (; i < NV; i += stride) {
        int4 t = t4[i];
        int4 s = s4[i];
        if (t.x >= lo && t.x < hi) { int p = atomicAdd(&fill_pos[t.x], 1); csr_src[p] = s.x; }
        if (t.y >= lo && t.y < hi) { int p = atomicAdd(&fill_pos[t.y], 1); csr_src[p] = s.y; }
        if (t.z >= lo && t.z < hi) { int p = atomicAdd(&fill_pos[t.z], 1); csr_src[p] = s.z; }
        if (t.w >= lo && t.w < hi) { int p = atomicAdd(&fill_pos[t.w], 1); csr_src[p] = s.w; }
    }
}

// ---------------- x -> fp16 cast ----------------

__global__ void cast_x_kernel(const float* __restrict__ x, __half* __restrict__ xh) {
    int i = blockIdx.x * blockDim.x + threadIdx.x; // one float4 per thread
    constexpr int TOT = N_NODESC * F_INC / 4;
    if (i >= TOT) return;
    float4 v = ((const float4*)x)[i];
    union { __half2 h[2]; uint2 u; } pk;
    pk.h[0] = __floats2half2_rn(v.x, v.y);
    pk.h[1] = __floats2half2_rn(v.z, v.w);
    ((uint2*)xh)[i] = pk.u;
}

// ---------------- K1: mean-gather x (fp16) -> agg (fp32, scaled) ----------------

__global__ __launch_bounds__(256) void gather1_kernel(
    const __half* __restrict__ xh, const int* __restrict__ row_ptr,
    const int* __restrict__ csr_src, const float* __restrict__ inv_deg,
    float* __restrict__ agg) {
    int gt = blockIdx.x * blockDim.x + threadIdx.x;
    int n = gt >> 2, l = gt & 3;
    if (n >= N_NODESC) return;

    float a[F_INC];
#pragma unroll
    for (int k = 0; k < F_INC; k++) a[k] = 0.0f;

    int e0 = row_ptr[n], e1 = row_ptr[n + 1];
    int e = e0 + l;
    // unroll-2: two independent gather streams in flight
    for (; e + 4 < e1; e += 8) {
        int s0 = csr_src[e];
        int s1 = csr_src[e + 4];
        const uint4* r0 = (const uint4*)(xh + (size_t)s0 * F_INC);
        const uint4* r1 = (const uint4*)(xh + (size_t)s1 * F_INC);
        uint4 u0 = r0[0], u1 = r0[1];
        uint4 w0 = r1[0], w1 = r1[1];
        const __half2* p;
        p = (const __half2*)&u0;
#pragma unroll
        for (int q = 0; q < 4; q++) { float2 f = __half22float2(p[q]); a[2*q] += f.x; a[2*q+1] += f.y; }
        p = (const __half2*)&u1;
#pragma unroll
        for (int q = 0; q < 4; q++) { float2 f = __half22float2(p[q]); a[8+2*q] += f.x; a[8+2*q+1] += f.y; }
        p = (const __half2*)&w0;
#pragma unroll
        for (int q = 0; q < 4; q++) { float2 f = __half22float2(p[q]); a[2*q] += f.x; a[2*q+1] += f.y; }
        p = (const __half2*)&w1;
#pragma unroll
        for (int q = 0; q < 4; q++) { float2 f = __half22float2(p[q]); a[8+2*q] += f.x; a[8+2*q+1] += f.y; }
    }
    if (e < e1) {
        int s0 = csr_src[e];
        const uint4* r0 = (const uint4*)(xh + (size_t)s0 * F_INC);
        uint4 u0 = r0[0], u1 = r0[1];
        const __half2* p = (const __half2*)&u0;
#pragma unroll
        for (int q = 0; q < 4; q++) { float2 f = __half22float2(p[q]); a[2*q] += f.x; a[2*q+1] += f.y; }
        p = (const __half2*)&u1;
#pragma unroll
        for (int q = 0; q < 4; q++) { float2 f = __half22float2(p[q]); a[8+2*q] += f.x; a[8+2*q+1] += f.y; }
    }

    // butterfly reduce across the 4 lanes of this node
#pragma unroll
    for (int off = 1; off <= 2; off <<= 1) {
#pragma unroll
        for (int k = 0; k < F_INC; k++) a[k] += __shfl_xor(a[k], off);
    }

    float idg = inv_deg[n];
    float4 w;
    w.x = a[l*4+0] * idg; w.y = a[l*4+1] * idg;
    w.z = a[l*4+2] * idg; w.w = a[l*4+3] * idg;
    ((float4*)(agg + (size_t)n * F_INC))[l] = w;
}

// ------- K2: dense fused: h=relu(agg@W1l+b1+x@W1r); g=h@W2l (fp16); r=h@W2r+b2 -------

__global__ __launch_bounds__(256) void dense_kernel(
    const float* __restrict__ x, const float* __restrict__ agg,
    const float* __restrict__ W1l, const float* __restrict__ b1,
    const float* __restrict__ W1r, const float* __restrict__ W2l,
    const float* __restrict__ b2, const float* __restrict__ W2r,
    __half* __restrict__ g16, float* __restrict__ r) {
    __shared__ float sW1l[F_INC][F_HC];
    __shared__ float sW1r[F_INC][F_HC];
    __shared__ float sb1[F_HC];
    __shared__ float sW2l[F_HC][F_OUTC];
    __shared__ float sW2r[F_HC][F_OUTC];
    __shared__ float sb2[F_OUTC];
    for (int i = threadIdx.x; i < F_INC * F_HC; i += blockDim.x) {
        sW1l[i / F_HC][i % F_HC] = W1l[i];
        sW1r[i / F_HC][i % F_HC] = W1r[i];
    }
    for (int i = threadIdx.x; i < F_HC * F_OUTC; i += blockDim.x) {
        sW2l[i / F_OUTC][i % F_OUTC] = W2l[i];
        sW2r[i / F_OUTC][i % F_OUTC] = W2r[i];
    }
    if (threadIdx.x < F_HC) sb1[threadIdx.x] = b1[threadIdx.x];
    if (threadIdx.x < F_OUTC) sb2[threadIdx.x] = b2[threadIdx.x];
    __syncthreads();

    int n = blockIdx.x * blockDim.x + threadIdx.x;
    if (n >= N_NODESC) return;

    float ag[F_INC], xr[F_INC];
    const float4* ap = (const float4*)(agg + (size_t)n * F_INC);
    const float4* xp = (const float4*)(x + (size_t)n * F_INC);
#pragma unroll
    for (int q = 0; q < F_INC / 4; q++) {
        float4 v = ap[q];
        ag[4*q] = v.x; ag[4*q+1] = v.y; ag[4*q+2] = v.z; ag[4*q+3] = v.w;
        float4 u = xp[q];
        xr[4*q] = u.x; xr[4*q+1] = u.y; xr[4*q+2] = u.z; xr[4*q+3] = u.w;
    }

    float h[F_HC];
#pragma unroll
    for (int f = 0; f < F_HC; f++) h[f] = sb1[f];
#pragma unroll
    for (int k = 0; k < F_INC; k++) {
        float a = ag[k], b = xr[k];
#pragma unroll
        for (int f = 0; f < F_HC; f++) h[f] += a * sW1l[k][f] + b * sW1r[k][f];
    }
#pragma unroll
    for (int f = 0; f < F_HC; f++) h[f] = fmaxf(h[f], 0.0f);

    float g[F_OUTC], rr[F_OUTC];
#pragma unroll
    for (int f = 0; f < F_OUTC; f++) { g[f] = 0.0f; rr[f] = sb2[f]; }
#pragma unroll
    for (int k = 0; k < F_HC; k++) {
        float hv = h[k];
#pragma unroll
        for (int f = 0; f < F_OUTC; f++) {
            g[f] += hv * sW2l[k][f];
            rr[f] += hv * sW2r[k][f];
        }
    }

    // g -> fp16, 64B-stride rows (32 halves, 24 used)
    __half* gp = g16 + (size_t)n * 32;
#pragma unroll
    for (int q = 0; q < F_OUTC / 8; q++) {
        union { __half2 h2[4]; uint4 u; } pk;
#pragma unroll
        for (int j = 0; j < 4; j++)
            pk.h2[j] = __floats2half2_rn(g[8*q + 2*j], g[8*q + 2*j + 1]);
        ((uint4*)gp)[q] = pk.u;
    }
    float4* rp = (float4*)(r + (size_t)n * F_OUTC);
#pragma unroll
    for (int q = 0; q < F_OUTC / 4; q++) {
        float4 v;
        v.x = rr[4*q]; v.y = rr[4*q+1]; v.z = rr[4*q+2]; v.w = rr[4*q+3];
        rp[q] = v;
    }
}

// ------- K3: mean-gather g (fp16) + r -> log_softmax -> out -------

__global__ __launch_bounds__(256) void gather2_kernel(
    const __half* __restrict__ g16, const int* __restrict__ row_ptr,
    const int* __restrict__ csr_src, const float* __restrict__ inv_deg,
    const float* __restrict__ r, float* __restrict__ out) {
    int gt = blockIdx.x * blockDim.x + threadIdx.x;
    int n = gt >> 2, l = gt & 3;
    if (n >= N_NODESC) return;

    float a[F_OUTC];
#pragma unroll
    for (int k = 0; k < F_OUTC; k++) a[k] = 0.0f;

    int e0 = row_ptr[n], e1 = row_ptr[n + 1];
    int e = e0 + l;
    for (; e + 4 < e1; e += 8) {
        int s0 = csr_src[e];
        int s1 = csr_src[e + 4];
        const uint4* r0 = (const uint4*)(g16 + (size_t)s0 * 32);
        const uint4* r1 = (const uint4*)(g16 + (size_t)s1 * 32);
        uint4 u0 = r0[0], u1 = r0[1], u2 = r0[2];
        uint4 w0 = r1[0], w1 = r1[1], w2 = r1[2];
        const __half2* p;
        p = (const __half2*)&u0;
#pragma unroll
        for (int q = 0; q < 4; q++) { float2 f = __half22float2(p[q]); a[2*q] += f.x; a[2*q+1] += f.y; }
        p = (const __half2*)&u1;
#pragma unroll
        for (int q = 0; q < 4; q++) { float2 f = __half22float2(p[q]); a[8+2*q] += f.x; a[8+2*q+1] += f.y; }
        p = (const __half2*)&u2;
#pragma unroll
        for (int q = 0; q < 4; q++) { float2 f = __half22float2(p[q]); a[16+2*q] += f.x; a[16+2*q+1] += f.y; }
        p = (const __half2*)&w0;
#pragma unroll
        for (int q = 0; q < 4; q++) { float2 f = __half22float2(p[q]); a[2*q] += f.x; a[2*q+1] += f.y; }
        p = (const __half2*)&w1;
#pragma unroll
        for (int q = 0; q < 4; q++) { float2 f = __half22float2(p[q]); a[8+2*q] += f.x; a[8+2*q+1] += f.y; }
        p = (const __half2*)&w2;
#pragma unroll
        for (int q = 0; q < 4; q++) { float2 f = __half22float2(p[q]); a[16+2*q] += f.x; a[16+2*q+1] += f.y; }
    }
    if (e < e1) {
        int s0 = csr_src[e];
        const uint4* r0 = (const uint4*)(g16 + (size_t)s0 * 32);
        uint4 u0 = r0[0], u1 = r0[1], u2 = r0[2];
        const __half2* p = (const __half2*)&u0;
#pragma unroll
        for (int q = 0; q < 4; q++) { float2 f = __half22float2(p[q]); a[2*q] += f.x; a[2*q+1] += f.y; }
        p = (const __half2*)&u1;
#pragma unroll
        for (int q = 0; q < 4; q++) { float2 f = __half22float2(p[q]); a[8+2*q] += f.x; a[8+2*q+1] += f.y; }
        p = (const __half2*)&u2;
#pragma unroll
        for (int q = 0; q < 4; q++) { float2 f = __half22float2(p[q]); a[16+2*q] += f.x; a[16+2*q+1] += f.y; }
    }

#pragma unroll
    for (int off = 1; off <= 2; off <<= 1) {
#pragma unroll
        for (int k = 0; k < F_OUTC; k++) a[k] += __shfl_xor(a[k], off);
    }

    float idg = inv_deg[n];
    const float* rb = r + (size_t)n * F_OUTC + l * 6;
    float o[6];
#pragma unroll
    for (int j = 0; j < 6; j++) o[j] = a[l * 6 + j] * idg + rb[j];

    float m = o[0];
#pragma unroll
    for (int j = 1; j < 6; j++) m = fmaxf(m, o[j]);
    m = fmaxf(m, __shfl_xor(m, 1));
    m = fmaxf(m, __shfl_xor(m, 2));
    float s = 0.0f;
#pragma unroll
    for (int j = 0; j < 6; j++) s += __expf(o[j] - m);
    s += __shfl_xor(s, 1);
    s += __shfl_xor(s, 2);
    float lse = m + __logf(s);

    float* ob = out + (size_t)n * F_OUTC + l * 6;
#pragma unroll
    for (int j = 0; j < 6; j++) ob[j] = o[j] - lse;
}

// ---------------- launch ----------------

extern "C" void kernel_launch(void* const* d_in, const int* in_sizes, int n_in,
                              void* d_out, int out_size, void* d_ws, size_t ws_size,
                              hipStream_t stream) {
    const float* x   = (const float*)d_in[0];
    const int* eidx  = (const int*)d_in[1];
    const float* W1l = (const float*)d_in[2];
    const float* b1  = (const float*)d_in[3];
    const float* W1r = (const float*)d_in[4];
    const float* W2l = (const float*)d_in[5];
    const float* b2  = (const float*)d_in[6];
    const float* W2r = (const float*)d_in[7];
    float* out = (float*)d_out;

    const int* src = eidx;
    const int* tgt = eidx + N_EDGESC;

    char* ws = (char*)d_ws;
    size_t off = 0;
    auto alloc = [&](size_t bytes) {
        size_t o = off;
        off = (off + bytes + 255) & ~(size_t)255;
        return o;
    };
    int*    deg      = (int*)(ws + alloc((size_t)N_NODESC * 4));
    int*    fill_pos = (int*)(ws + alloc((size_t)N_NODESC * 4));
    float*  inv_deg  = (float*)(ws + alloc((size_t)N_NODESC * 4));
    int*    row_ptr  = (int*)(ws + alloc((size_t)(N_NODESC + 1) * 4));
    int*    bsum     = (int*)(ws + alloc((size_t)NBLK * 4));
    int*    csr_src  = (int*)(ws + alloc((size_t)N_EDGESC * 4));
    __half* xh       = (__half*)(ws + alloc((size_t)N_NODESC * F_INC * 2));
    float*  agg      = (float*)(ws + alloc((size_t)N_NODESC * F_INC * 4));
    __half* g16      = (__half*)(ws + alloc((size_t)N_NODESC * 32 * 2));
    float*  r        = (float*)(ws + alloc((size_t)N_NODESC * F_OUTC * 4));
    (void)ws_size;

    hipMemsetAsync(deg, 0, (size_t)N_NODESC * 4, stream);

    const int TB = 256;
    const int edgeBlocks = 2560; // multiple of 8 (deg/fill bucketing requires it)
    deg_kernel<<<edgeBlocks, TB, 0, stream>>>(tgt, deg);
    cast_x_kernel<<<(N_NODESC * F_INC / 4 + TB - 1) / TB, TB, 0, stream>>>(x, xh);
    scan1_kernel<<<NBLK, SCAN_BLOCK, 0, stream>>>(deg, inv_deg, row_ptr, bsum);
    scan2_kernel<<<1, 256, 0, stream>>>(bsum);
    scan3_kernel<<<NBLK, SCAN_BLOCK, 0, stream>>>(row_ptr, bsum, fill_pos);
    fill_kernel<<<edgeBlocks, TB, 0, stream>>>(src, tgt, fill_pos, csr_src);

    const int lane4Blocks = ((N_NODESC * 4) + TB - 1) / TB; // 3125
    gather1_kernel<<<lane4Blocks, TB, 0, stream>>>(xh, row_ptr, csr_src, inv_deg, agg);
    dense_kernel<<<(N_NODESC + TB - 1) / TB, TB, 0, stream>>>(
        x, agg, W1l, b1, W1r, W2l, b2, W2r, g16, r);
    gather2_kernel<<<lane4Blocks, TB, 0, stream>>>(g16, row_ptr, csr_src, inv_deg, r, out);
}